// Round 1
// baseline (2755.540 us; speedup 1.0000x reference)
//
#include <hip/hip_runtime.h>

#define NN 100000
#define NE 1600000

typedef short s8v __attribute__((ext_vector_type(8)));
typedef float f32x4 __attribute__((ext_vector_type(4)));
typedef unsigned short u16;

__device__ __forceinline__ u16 f2bf(float f) {
    union { float f; unsigned u; } v; v.f = f;
    unsigned r = v.u + 0x7FFFu + ((v.u >> 16) & 1u);
    return (u16)(r >> 16);
}
__device__ __forceinline__ unsigned pk2(float a, float b) {
    return (unsigned)f2bf(a) | ((unsigned)f2bf(b) << 16);
}

// ---------------- weight fragment packing (bf16, B-operand layout) -------------
// frag f at wpack + f*512: lane L holds 8 contiguous bf16 = B[k = s*32+(L>>4)*8+j][n = t*16+(L&15)]
// order: pW (16 frags) | per layer l: eW1 (24) eW2 (8) nW1 (16) nW2 (8)
__global__ void pack_weights(const float* __restrict__ pW,
                             const float* __restrict__ eW1, const float* __restrict__ eW2,
                             const float* __restrict__ nW1, const float* __restrict__ nW2,
                             u16* __restrict__ wpack) {
    int b = blockIdx.x, L = threadIdx.x;
    const float* src; int s, t;
    if (b < 16) { src = pW; s = b >> 2; t = b & 3; }
    else {
        int bb = b - 16, l = bb / 56, r = bb % 56;
        if (r < 24)      {            src = eW1 + l*192*64; s = r>>2; t = r&3; }
        else if (r < 32) { r -= 24;   src = eW2 + l*64*64;  s = r>>2; t = r&3; }
        else if (r < 48) { r -= 32;   src = nW1 + l*128*64; s = r>>2; t = r&3; }
        else             { r -= 48;   src = nW2 + l*64*64;  s = r>>2; t = r&3; }
    }
    int kbase = s*32 + (L>>4)*8;
    int n = t*16 + (L&15);
    u16* dst = wpack + (size_t)b*512 + (size_t)L*8;
#pragma unroll
    for (int j = 0; j < 8; ++j) dst[j] = f2bf(src[(kbase+j)*64 + n]);
}

// ---------------- node projection: h = x @ pW + pb (bf16 MFMA) -----------------
__global__ __launch_bounds__(256) void node_proj(const float* __restrict__ x,
                                                 const float* __restrict__ pb,
                                                 const u16* __restrict__ wpack,
                                                 float* __restrict__ h,
                                                 u16* __restrict__ h_bf) {
    __shared__ __align__(16) u16 sX[64*136];   // 64 nodes x 128, stride 136 (2-way banks, free)
    const int tid = threadIdx.x;
    const int n0 = blockIdx.x * 64;
    for (int i = tid; i < 64*32; i += 256) {
        int node = i >> 5, c = i & 31;
        float4 v = make_float4(0.f, 0.f, 0.f, 0.f);
        if (n0 + node < NN) v = *(const float4*)(x + (size_t)(n0+node)*128 + c*4);
        *(uint2*)&sX[node*136 + c*4] = make_uint2(pk2(v.x, v.y), pk2(v.z, v.w));
    }
    __syncthreads();
    const int w = tid >> 6, L = tid & 63;
    const int m = L & 15, kc = L >> 4;
    const int wb = w * 16;
    const f32x4 z = {0.f, 0.f, 0.f, 0.f};
    f32x4 acc[4] = {z, z, z, z};
#pragma unroll
    for (int s = 0; s < 4; ++s) {
        s8v a = *(const s8v*)&sX[(wb+m)*136 + s*32 + kc*8];
#pragma unroll
        for (int t = 0; t < 4; ++t) {
            s8v bf = *(const s8v*)(wpack + ((size_t)(s*4+t)*64 + L)*8);
            acc[t] = __builtin_amdgcn_mfma_f32_16x16x32_bf16(a, bf, acc[t], 0, 0, 0);
        }
    }
#pragma unroll
    for (int t = 0; t < 4; ++t) {
        int u = t*16 + m;
        float bias = pb[u];
#pragma unroll
        for (int r = 0; r < 4; ++r) {
            int node = n0 + wb + kc*4 + r;
            if (node < NN) {
                float v = acc[t][r] + bias;
                h[(size_t)node*64 + u] = v;
                h_bf[(size_t)node*64 + u] = f2bf(v);
            }
        }
    }
}

// ---------------- fused per-layer edge kernel ----------------------------------
// block: 256 thr / 4 waves, 128 edges; wave owns 32 edge-rows after one barrier.
__global__ __launch_bounds__(256) void edge_layer(const int* __restrict__ ei,
                                                  const float* __restrict__ ea_f32,
                                                  const u16* __restrict__ h_bf,
                                                  u16* __restrict__ ea_bf,
                                                  const u16* __restrict__ wp,
                                                  const float* __restrict__ eb1,
                                                  const float* __restrict__ eb2,
                                                  const float* __restrict__ nb1,
                                                  const float* __restrict__ nb2,
                                                  float* __restrict__ agg, int first) {
    __shared__ __align__(16) u16 sAct[128*200];   // [h_row(64)|h_col(64)|ea(64)], stride 200
    __shared__ __align__(16) u16 sT[128*72];      // t1/t2, stride 72
    __shared__ int sCol[128];
    const int tid = threadIdx.x;
    const int e0 = blockIdx.x * 128;
    if (tid < 128) sCol[tid] = ei[(size_t)NE + e0 + tid];
    for (int i = tid; i < 128*24; i += 256) {
        int e = i / 24, c = i % 24;
        int reg = c >> 3, wc = c & 7;
        uint4 val;
        if (reg == 2) {
            if (first) {
                const float* s = ea_f32 + (size_t)(e0+e)*64 + wc*8;
                float4 v0 = *(const float4*)s;
                float4 v1 = *(const float4*)(s + 4);
                val.x = pk2(v0.x, v0.y); val.y = pk2(v0.z, v0.w);
                val.z = pk2(v1.x, v1.y); val.w = pk2(v1.z, v1.w);
            } else {
                val = *(const uint4*)(ea_bf + (size_t)(e0+e)*64 + wc*8);
            }
        } else {
            int idx = ei[(size_t)reg*NE + e0 + e];
            val = *(const uint4*)(h_bf + (size_t)idx*64 + wc*8);
        }
        *(uint4*)&sAct[e*200 + c*8] = val;
    }
    __syncthreads();

    const int w = tid >> 6, L = tid & 63;
    const int m = L & 15, kc = L >> 4;
    const int wb = w * 32;
    float be1[4], be2[4], bn1[4], bn2[4];
#pragma unroll
    for (int t = 0; t < 4; ++t) {
        int u = t*16 + m;
        be1[t] = eb1[u]; be2[t] = eb2[u]; bn1[t] = nb1[u]; bn2[t] = nb2[u];
    }
    const f32x4 z = {0.f, 0.f, 0.f, 0.f};
    f32x4 acc[2][4];

    // ---- GEMM1: ein[*,192] @ eW1 -> t1 (relu) ----
#pragma unroll
    for (int g = 0; g < 2; ++g)
#pragma unroll
        for (int t = 0; t < 4; ++t) acc[g][t] = z;
#pragma unroll
    for (int s = 0; s < 6; ++s) {
        s8v a0 = *(const s8v*)&sAct[(wb + m)*200 + s*32 + kc*8];
        s8v a1 = *(const s8v*)&sAct[(wb + 16 + m)*200 + s*32 + kc*8];
#pragma unroll
        for (int t = 0; t < 4; ++t) {
            s8v bf = *(const s8v*)(wp + ((size_t)(s*4+t)*64 + L)*8);
            acc[0][t] = __builtin_amdgcn_mfma_f32_16x16x32_bf16(a0, bf, acc[0][t], 0, 0, 0);
            acc[1][t] = __builtin_amdgcn_mfma_f32_16x16x32_bf16(a1, bf, acc[1][t], 0, 0, 0);
        }
    }
#pragma unroll
    for (int g = 0; g < 2; ++g)
#pragma unroll
        for (int t = 0; t < 4; ++t) {
            int u = t*16 + m;
#pragma unroll
            for (int r = 0; r < 4; ++r) {
                float v = acc[g][t][r] + be1[t];
                v = v > 0.f ? v : 0.f;
                sT[(wb + g*16 + kc*4 + r)*72 + u] = f2bf(v);
            }
        }

    // ---- GEMM2: t1 @ eW2 -> ea_new ----
    const u16* wp2 = wp + 24*512;
#pragma unroll
    for (int g = 0; g < 2; ++g)
#pragma unroll
        for (int t = 0; t < 4; ++t) acc[g][t] = z;
#pragma unroll
    for (int s = 0; s < 2; ++s) {
        s8v a0 = *(const s8v*)&sT[(wb + m)*72 + s*32 + kc*8];
        s8v a1 = *(const s8v*)&sT[(wb + 16 + m)*72 + s*32 + kc*8];
#pragma unroll
        for (int t = 0; t < 4; ++t) {
            s8v bf = *(const s8v*)(wp2 + ((size_t)(s*4+t)*64 + L)*8);
            acc[0][t] = __builtin_amdgcn_mfma_f32_16x16x32_bf16(a0, bf, acc[0][t], 0, 0, 0);
            acc[1][t] = __builtin_amdgcn_mfma_f32_16x16x32_bf16(a1, bf, acc[1][t], 0, 0, 0);
        }
    }
#pragma unroll
    for (int g = 0; g < 2; ++g)
#pragma unroll
        for (int t = 0; t < 4; ++t) {
            int u = t*16 + m;
#pragma unroll
            for (int r = 0; r < 4; ++r) {
                float v = acc[g][t][r] + be2[t];
                u16 bv = f2bf(v);
                int er = wb + g*16 + kc*4 + r;
                sAct[er*200 + 128 + u] = bv;                   // overwrite ea slot (own rows)
                ea_bf[(size_t)(e0+er)*64 + u] = bv;            // persist for next layer
            }
        }

    // ---- GEMM3: [h_row|ea_new][*,128] @ nW1 -> t2 (relu) ----
    const u16* wp3 = wp + 32*512;
#pragma unroll
    for (int g = 0; g < 2; ++g)
#pragma unroll
        for (int t = 0; t < 4; ++t) acc[g][t] = z;
#pragma unroll
    for (int s = 0; s < 4; ++s) {
        int c = s*4 + kc;
        int off = c*8 + (c >= 8 ? 64 : 0);   // skip h_col region
        s8v a0 = *(const s8v*)&sAct[(wb + m)*200 + off];
        s8v a1 = *(const s8v*)&sAct[(wb + 16 + m)*200 + off];
#pragma unroll
        for (int t = 0; t < 4; ++t) {
            s8v bf = *(const s8v*)(wp3 + ((size_t)(s*4+t)*64 + L)*8);
            acc[0][t] = __builtin_amdgcn_mfma_f32_16x16x32_bf16(a0, bf, acc[0][t], 0, 0, 0);
            acc[1][t] = __builtin_amdgcn_mfma_f32_16x16x32_bf16(a1, bf, acc[1][t], 0, 0, 0);
        }
    }
#pragma unroll
    for (int g = 0; g < 2; ++g)
#pragma unroll
        for (int t = 0; t < 4; ++t) {
            int u = t*16 + m;
#pragma unroll
            for (int r = 0; r < 4; ++r) {
                float v = acc[g][t][r] + bn1[t];
                v = v > 0.f ? v : 0.f;
                sT[(wb + g*16 + kc*4 + r)*72 + u] = f2bf(v);
            }
        }

    // ---- GEMM4: t2 @ nW2 -> msg; scatter-add ----
    const u16* wp4 = wp + 48*512;
#pragma unroll
    for (int g = 0; g < 2; ++g)
#pragma unroll
        for (int t = 0; t < 4; ++t) acc[g][t] = z;
#pragma unroll
    for (int s = 0; s < 2; ++s) {
        s8v a0 = *(const s8v*)&sT[(wb + m)*72 + s*32 + kc*8];
        s8v a1 = *(const s8v*)&sT[(wb + 16 + m)*72 + s*32 + kc*8];
#pragma unroll
        for (int t = 0; t < 4; ++t) {
            s8v bf = *(const s8v*)(wp4 + ((size_t)(s*4+t)*64 + L)*8);
            acc[0][t] = __builtin_amdgcn_mfma_f32_16x16x32_bf16(a0, bf, acc[0][t], 0, 0, 0);
            acc[1][t] = __builtin_amdgcn_mfma_f32_16x16x32_bf16(a1, bf, acc[1][t], 0, 0, 0);
        }
    }
#pragma unroll
    for (int g = 0; g < 2; ++g)
#pragma unroll
        for (int t = 0; t < 4; ++t) {
            int u = t*16 + m;
#pragma unroll
            for (int r = 0; r < 4; ++r) {
                int er = wb + g*16 + kc*4 + r;
                unsafeAtomicAdd(&agg[(size_t)sCol[er]*64 + u], acc[g][t][r] + bn2[t]);
            }
        }
}

// ---------------- h = relu(agg + h); refresh bf16 copy -------------------------
__global__ void update_h(float* __restrict__ h, const float* __restrict__ agg,
                         u16* __restrict__ h_bf) {
    int i = (blockIdx.x * 256 + threadIdx.x) * 4;
    float4 a = *(const float4*)(agg + i);
    float4 hv = *(const float4*)(h + i);
    float4 v;
    v.x = fmaxf(a.x + hv.x, 0.f);
    v.y = fmaxf(a.y + hv.y, 0.f);
    v.z = fmaxf(a.z + hv.z, 0.f);
    v.w = fmaxf(a.w + hv.w, 0.f);
    *(float4*)(h + i) = v;
    *(uint2*)(h_bf + i) = make_uint2(pk2(v.x, v.y), pk2(v.z, v.w));
}

// ---------------- mean pool (stage 1: block partials -> atomics) ---------------
__global__ void pool1(const float* __restrict__ h, float* __restrict__ pooled) {
    float acc = 0.f;
    const int stride = gridDim.x * 256;
    for (int i = blockIdx.x * 256 + threadIdx.x; i < NN*64; i += stride)
        acc += h[i];
    __shared__ float sp[256];
    sp[threadIdx.x] = acc;
    __syncthreads();
    if (threadIdx.x < 64) {
        float v = sp[threadIdx.x] + sp[threadIdx.x+64] + sp[threadIdx.x+128] + sp[threadIdx.x+192];
        unsafeAtomicAdd(&pooled[threadIdx.x], v);
    }
}

// ---------------- final linear: out = (pooled/N) @ lW + lb ---------------------
__global__ void pool2(const float* __restrict__ pooled, const float* __restrict__ lW,
                      const float* __restrict__ lb, float* __restrict__ out) {
    int k = threadIdx.x;   // 64 threads
    float v = pooled[k] * (1.0f / NN);
#pragma unroll
    for (int o = 0; o < 3; ++o) {
        float p = v * lW[k*3 + o];
        for (int off = 32; off > 0; off >>= 1)
            p += __shfl_down(p, off);
        if (k == 0) out[o] = p + lb[o];
    }
}

extern "C" void kernel_launch(void* const* d_in, const int* in_sizes, int n_in,
                              void* d_out, int out_size, void* d_ws, size_t ws_size,
                              hipStream_t stream) {
    const float* x         = (const float*)d_in[0];
    const int*   ei        = (const int*)d_in[1];
    const float* edge_attr = (const float*)d_in[2];
    const float* pW        = (const float*)d_in[3];
    const float* pb        = (const float*)d_in[4];
    const float* eW1       = (const float*)d_in[5];
    const float* eb1       = (const float*)d_in[6];
    const float* eW2       = (const float*)d_in[7];
    const float* eb2       = (const float*)d_in[8];
    const float* nW1       = (const float*)d_in[9];
    const float* nb1       = (const float*)d_in[10];
    const float* nW2       = (const float*)d_in[11];
    const float* nb2       = (const float*)d_in[12];
    const float* lW        = (const float*)d_in[13];
    const float* lb        = (const float*)d_in[14];
    float* out = (float*)d_out;

    char* ws = (char*)d_ws;
    float* h     = (float*)(ws);                         // 25,600,000 B
    float* agg   = (float*)(ws + 25600000);              // 25,600,000 B
    u16*   h_bf  = (u16*)  (ws + 51200000);              // 12,800,000 B
    u16*   ea_bf = (u16*)  (ws + 64000000);              // 204,800,000 B
    u16*   wpack = (u16*)  (ws + 268800000);             // 188,416 B
    float* pooled= (float*)(ws + 268988416);             // 256 B

    pack_weights<<<184, 64, 0, stream>>>(pW, eW1, eW2, nW1, nW2, wpack);
    node_proj<<<(NN + 63)/64, 256, 0, stream>>>(x, pb, wpack, h, h_bf);
    for (int l = 0; l < 3; ++l) {
        hipMemsetAsync(agg, 0, (size_t)NN*64*4, stream);
        edge_layer<<<NE/128, 256, 0, stream>>>(ei, edge_attr, h_bf, ea_bf,
                                               wpack + (16 + l*56)*512,
                                               eb1 + l*64, eb2 + l*64, nb1 + l*64, nb2 + l*64,
                                               agg, l == 0 ? 1 : 0);
        update_h<<<NN*64/4/256, 256, 0, stream>>>(h, agg, h_bf);
    }
    hipMemsetAsync(pooled, 0, 64*4, stream);
    pool1<<<256, 256, 0, stream>>>(h, pooled);
    pool2<<<1, 64, 0, stream>>>(pooled, lW, lb, out);
}